// Round 10
// baseline (323.268 us; speedup 1.0000x reference)
//
#include <hip/hip_runtime.h>

#define HH 512
#define WW 512
#define NIMG 12
#define RAD 3
#define TW 64
#define TH 32
#define LW (TW + 2*RAD)   // 70
#define RPW 8             // output rows per wave (TH / 4 waves)
#define SLABR (RPW + 6)   // 14: rows in a wave's private window

typedef float v2 __attribute__((ext_vector_type(2)));

#define GPTR const __attribute__((address_space(1))) void*
#define LPTR __attribute__((address_space(3))) void*

// R10: barrier-free per-wave private staging.
//
// SESSION LEDGER:
//  R1 fuse2 48KB LDS: 256us (occ 18.6, latency-bound).
//  R2 fuse2 + bounds(256,4): 554us. VGPR clamp 64 < ring ~90 -> spill.
//  R3 fuse2 TH=16: 276us. VGPR tier pins 4 waves/SIMD regardless of LDS.
//  R4 unfused + pi-pair ring: 225.5us. Wall = ~20us issue + stall.
//  R5 streaming + bounds(256,8): 363us. Clamp -> VGPR 32 -> spill.
//  R6 streaming unclamped: 252us. Allocator floats >64; +12% issue.
//  R7 streaming + retire-early + sched_barrier: 255.7us. Arc closed.
//  R8 R4 + global_load_lds interior staging: 221.3us.
//  R9 TH=32/RPW=8 (prologue+halo amortization): 207.0us BEST. Twice-
//     confirmed: per-wave/per-block overhead amortization is the margin.
//  R10: the last structural serializer is __syncthreads' vmcnt(0) drain
//     (all 4 waves idle until the slowest staging load). No block
//     cooperation is actually needed: each wave stages ITS OWN 14-row
//     window into a PRIVATE LDS slab -> no barrier at all, per-wave
//     self-drain, 16 independent waves/CU free to overlap staging with
//     compute. Cost: 56 rows staged vs 38 (+47% fetch, ~0.6% of HBM
//     peak -- the FETCH rise is the confirmation signature).
//
// NUMERICS CONTRACT (harness-validated R1-R9, absmax 9.77e-4 exactly):
//  - conv = sequential fma over the 7x7 window, (ky,kx) row-major, one
//    accumulator per direction (bit-exact im path vs the fp32 ref replay).
//  - L/R, NW/NE, SW/SE packed as v_pk_fma lanes; each lane's tap sequence
//    identical to the scalar chain. U/D scalar chains, same tap order.
//  - pi[s][d] = {row[tx+d], row[tx+d+3]}: exactly the operand pair of
//    every packed chain -> zero packing movs.
//  - PERT: quadrant decomposition, trees unchanged since prior-session R5.
//  - Private slabs change WHERE rows are staged, not their values: every
//    output row still consumes the identical 7-row window in identical
//    order -> bit-identical.
template <int NR, int LDW, class F>
__device__ __forceinline__ void ring_pass(
    const float* __restrict__ SI, const float* __restrict__ SP,
    int r0, int tx, F emit)
{
    const float w28 = 1.0f / 28.0f;   // fp32-rounded, as in the ref kernels
    const float w16 = 0.0625f;        // exact
    const v2 w28v = {w28, w28};
    const v2 w16v = {w16, w16};

    v2    pi[7][4];   // pi[slot][d] = {row[tx+d], row[tx+d+3]}
    v2    hlr[7];     // pert row partials {hl, hr}
    float cc[7];      // pert center column

    auto rowload = [&](int slot, int m) {
        const float* rI = SI + m * LDW + tx;
        float w0 = rI[0], w1 = rI[1], w2 = rI[2], w3 = rI[3],
              w4 = rI[4], w5 = rI[5], w6 = rI[6];
        pi[slot][0] = (v2){w0, w3};
        pi[slot][1] = (v2){w1, w4};
        pi[slot][2] = (v2){w2, w5};
        pi[slot][3] = (v2){w3, w6};
        const float* rP = SP + m * LDW + tx;
        float b0 = rP[0], b1 = rP[1], b2 = rP[2], b3 = rP[3],
              b4 = rP[4], b5 = rP[5], b6 = rP[6];
        hlr[slot] = (v2){(b0 + b1) + (b2 + b3), (b3 + b4) + (b5 + b6)};
        cc[slot] = b3;
    };

    #pragma unroll
    for (int m = 0; m < 7; ++m)
        rowload(m, r0 + m);

    #pragma unroll
    for (int jj = 0; jj < NR; ++jj) {
        // ---- im: packed L/R, NW/NE, SW/SE + scalar U, D ----
        v2 aLR = {0.f, 0.f}, aQN = {0.f, 0.f}, aQS = {0.f, 0.f};
        #pragma unroll
        for (int dy = 0; dy < 7; ++dy) {
            const int s = (jj + dy) % 7;
            #pragma unroll
            for (int dx = 0; dx < 4; ++dx)   // L: cols 0..3 | R: cols 3..6
                aLR = __builtin_elementwise_fma(pi[s][dx], w28v, aLR);
        }
        float U = 0.f, Dd = 0.f;
        #pragma unroll
        for (int dy = 0; dy < 4; ++dy) {     // U rows 0..3 | D rows 3..6
            const int su = (jj + dy) % 7;
            const int sd = (jj + dy + 3) % 7;
            // cols 0..6 = pi[0].x pi[1].x pi[2].x pi[3].x pi[1].y pi[2].y pi[3].y
            U = fmaf(pi[su][0].x, w28, U);  U = fmaf(pi[su][1].x, w28, U);
            U = fmaf(pi[su][2].x, w28, U);  U = fmaf(pi[su][3].x, w28, U);
            U = fmaf(pi[su][1].y, w28, U);  U = fmaf(pi[su][2].y, w28, U);
            U = fmaf(pi[su][3].y, w28, U);
            Dd = fmaf(pi[sd][0].x, w28, Dd); Dd = fmaf(pi[sd][1].x, w28, Dd);
            Dd = fmaf(pi[sd][2].x, w28, Dd); Dd = fmaf(pi[sd][3].x, w28, Dd);
            Dd = fmaf(pi[sd][1].y, w28, Dd); Dd = fmaf(pi[sd][2].y, w28, Dd);
            Dd = fmaf(pi[sd][3].y, w28, Dd);
            #pragma unroll
            for (int dx = 0; dx < 4; ++dx) { // NW/NE top rows, SW/SE bottom
                aQN = __builtin_elementwise_fma(pi[su][dx], w16v, aQN);
                aQS = __builtin_elementwise_fma(pi[sd][dx], w16v, aQS);
            }
        }

        const float cI = pi[(jj + 3) % 7][3].x;   // center col 3
        const v2 cI2 = {cI, cI};
        const v2 d01 = aLR - cI2;
        const float d2 = U - cI, d3 = Dd - cI;
        const v2 d45 = aQN - cI2;
        const v2 d67 = aQS - cI2;
        float d[8] = {d01.x, d01.y, d2, d3, d45.x, d45.y, d67.x, d67.y};

        // ---- pert: packed quadrant decomposition (values identical R5) ----
        float e[8];
        const int p0 = (jj + 0) % 7, p1 = (jj + 1) % 7, p2 = (jj + 2) % 7,
                  p3 = (jj + 3) % 7, p4 = (jj + 4) % 7, p5 = (jj + 5) % 7,
                  p6 = (jj + 6) % 7;
        const float cP = cc[p3];
        {
            v2 qN = ((hlr[p0] + hlr[p1]) + (hlr[p2] + hlr[p3])); // (qnw,qne)
            v2 qS = ((hlr[p3] + hlr[p4]) + (hlr[p5] + hlr[p6])); // (qsw,qse)
            float cu = ((cc[p0] + cc[p1]) + (cc[p2] + cc[p3]));
            float cd = ((cc[p3] + cc[p4]) + (cc[p5] + cc[p6]));
            const v2 cP2 = {cP, cP};
            v2 eLR = (qN + qS - hlr[p3]) * w28v - cP2;   // (L, R)
            v2 eQN = qN * w16v - cP2;                    // (NW, NE)
            v2 eQS = qS * w16v - cP2;                    // (SW, SE)
            e[0] = eLR.x;  e[1] = eLR.y;
            e[2] = (qN.x + qN.y - cu) * w28 - cP;        // U
            e[3] = (qS.x + qS.y - cd) * w28 - cP;        // D
            e[4] = eQN.x;  e[5] = eQN.y;
            e[6] = eQS.x;  e[7] = eQS.y;
        }

        // first-index-wins argmin over |d| (jnp.argmin tie-break)
        float bestAbs = fabsf(d[0]);
        float bd = d[0];
        float be = e[0];
        #pragma unroll
        for (int j = 1; j < 8; ++j) {
            float a = fabsf(d[j]);
            bool take = a < bestAbs;
            bestAbs = take ? a : bestAbs;
            bd = take ? d[j] : bd;
            be = take ? e[j] : be;
        }

        emit(jj, cI + bd, cP + be);

        if (jj < NR - 1)
            rowload(jj % 7, r0 + jj + 7);
    }
}

__global__ __launch_bounds__(256) void swf_step(
    const float* __restrict__ im_in, const float* __restrict__ pe_in,
    float* __restrict__ im_out, float* __restrict__ pe_out, int storeIm)
{
    // Per-wave private slabs: no cross-wave LDS sharing -> no barrier.
    __shared__ float sI[4][SLABR * LW];   // 15.7 KB
    __shared__ float sP[4][SLABR * LW];   // 15.7 KB (total 31.4 KB)

    const int tid = threadIdx.x;
    const int tx = tid & 63;
    const int wv = tid >> 6;          // wave id 0..3
    const int x0 = blockIdx.x * TW;
    const int yw = blockIdx.y * TH + wv * RPW;   // wave's first output row
    const size_t base = (size_t)blockIdx.z * (size_t)(HH * WW);
    const float* imb = im_in + base;
    const float* peb = pe_in + base;

    float* slabI = &sI[wv][0];
    float* slabP = &sP[wv][0];

    // Wave's window: rows yw-3 .. yw+RPW+2, cols x0-3 .. x0+66.
    // Per-wave interior test (y-edge blocks keep 3/4 waves on fast path).
    const bool wInterior = (blockIdx.x >= 1) && (blockIdx.x <= 6) &&
                           (yw - RAD >= 0) && (yw + RPW + 2 < HH);
    if (wInterior) {
        #pragma unroll 1
        for (int r = 0; r < SLABR; ++r) {
            const float* gI = imb + (size_t)(yw - RAD + r) * WW + (x0 - RAD);
            const float* gP = peb + (size_t)(yw - RAD + r) * WW + (x0 - RAD);
            __builtin_amdgcn_global_load_lds((GPTR)(gI + tx),
                                             (LPTR)(&slabI[r * LW]), 4, 0, 0);
            __builtin_amdgcn_global_load_lds((GPTR)(gP + tx),
                                             (LPTR)(&slabP[r * LW]), 4, 0, 0);
            if (tx < 6) {
                __builtin_amdgcn_global_load_lds((GPTR)(gI + 64 + tx),
                                                 (LPTR)(&slabI[r * LW + 64]), 4, 0, 0);
                __builtin_amdgcn_global_load_lds((GPTR)(gP + 64 + tx),
                                                 (LPTR)(&slabP[r * LW + 64]), 4, 0, 0);
            }
        }
    } else {
        // Edge path: masked scalar staging with zero padding (per-wave).
        #pragma unroll 1
        for (int r = 0; r < SLABR; ++r) {
            const int gy = yw - RAD + r;
            const bool oky = (unsigned)gy < (unsigned)HH;
            {
                const int gx = x0 - RAD + tx;
                const bool ok = oky && ((unsigned)gx < (unsigned)WW);
                const int gi = gy * WW + gx;
                slabI[r * LW + tx] = ok ? imb[gi] : 0.0f;
                slabP[r * LW + tx] = ok ? peb[gi] : 0.0f;
            }
            if (tx < 6) {
                const int gx = x0 - RAD + 64 + tx;
                const bool ok = oky && ((unsigned)gx < (unsigned)WW);
                const int gi = gy * WW + gx;
                slabI[r * LW + 64 + tx] = ok ? imb[gi] : 0.0f;
                slabP[r * LW + 64 + tx] = ok ? peb[gi] : 0.0f;
            }
        }
    }
    // Per-wave self-drain of the global_load_lds queue. No __syncthreads
    // anywhere: the "memory" clobber also pins subsequent ds_reads after
    // this point (do not trust implicit ordering without a barrier).
    asm volatile("s_waitcnt vmcnt(0)" ::: "memory");

    ring_pass<RPW, LW>(slabI, slabP, 0, tx,
        [&](int jj, float vI, float vP) {
            const size_t gi = base + (size_t)(yw + jj) * WW + (x0 + tx);
            if (storeIm) im_out[gi] = vI;
            pe_out[gi] = vP;
        });
}

extern "C" void kernel_launch(void* const* d_in, const int* in_sizes, int n_in,
                              void* d_out, int out_size, void* d_ws, size_t ws_size,
                              hipStream_t stream) {
    const float* im0 = (const float*)d_in[0];
    const float* pe0 = (const float*)d_in[1];
    float* out = (float*)d_out;

    const size_t npix = (size_t)NIMG * HH * WW;   // 3,145,728
    float* imA = (float*)d_ws;                    // 12.6 MB
    float* imB = imA + npix;                      // 12.6 MB
    float* peA = imB + npix;                      // 12.6 MB (ws total 37.7 MB)
    float* peB = out;  // d_out doubles as the second pert buffer; parity
                       // lands the final (iter-5) pert write in d_out.

    dim3 grid(WW / TW, HH / TH, NIMG);            // 8 x 16 x 12 = 1536 blocks
    dim3 block(256);

    swf_step<<<grid, block, 0, stream>>>(im0, pe0, imA, peA, 1);  // iter 0
    swf_step<<<grid, block, 0, stream>>>(imA, peA, imB, peB, 1);  // iter 1
    swf_step<<<grid, block, 0, stream>>>(imB, peB, imA, peA, 1);  // iter 2
    swf_step<<<grid, block, 0, stream>>>(imA, peA, imB, peB, 1);  // iter 3
    swf_step<<<grid, block, 0, stream>>>(imB, peB, imA, peA, 1);  // iter 4
    // iter 5: im store is dead (result = filtered pert only) -> skip
    swf_step<<<grid, block, 0, stream>>>(imA, peA, imB, out, 0);  // iter 5
}

// Round 11
// 207.464 us; speedup vs baseline: 1.5582x; 1.5582x over previous
//
#include <hip/hip_runtime.h>

#define HH 512
#define WW 512
#define NIMG 12
#define RAD 3
#define TW 64
#define TH 32
#define LW (TW + 2*RAD)   // 70
#define LH (TH + 2*RAD)   // 38
#define RPW 8             // output rows per wave (TH / 4 waves)

typedef float v2 __attribute__((ext_vector_type(2)));

#define GPTR const __attribute__((address_space(1))) void*
#define LPTR __attribute__((address_space(3))) void*

// R11: exact R9 revert (best, 207.0us) + s_setprio(1) around the compute
// phase.
//
// SESSION LEDGER:
//  R1 fuse2 48KB LDS: 256us (occ 18.6, latency-bound).
//  R2 fuse2 + bounds(256,4): 554us. VGPR clamp 64 < ring ~90 -> spill.
//  R3 fuse2 TH=16: 276us. VGPR tier pins 4 waves/SIMD regardless of LDS.
//  R4 unfused + pi-pair ring: 225.5us. Wall = ~20us issue + stall.
//  R5 streaming + bounds(256,8): 363us. Clamp -> VGPR 32 -> spill.
//  R6 streaming unclamped: 252us. Allocator floats >64; +12% issue.
//  R7 streaming + retire-early + sched_barrier: 255.7us. Arc closed.
//  R8 R4 + global_load_lds interior staging: 221.3us.
//  R9 TH=32/RPW=8 (prologue+halo amortization): 207.0us BEST.
//  R10 barrier-free per-wave slabs: 323us (-56%!). Removing __syncthreads
//      destroyed the schedule (VALUBusy 45->23) despite FETCH staying
//      ~23MB. Mechanism unresolved; verdict: keep block-shared staging +
//      single barrier. Structural arcs all closed.
//  R11: R9 + setprio: at 4 blocks/CU, co-resident blocks sit at different
//      phases (staging vs ring compute) -> priority arbitration can favor
//      compute waves' VALU issue over staging waves' latency-insensitive
//      DMA issue (mechanism measured +4-7% on attn, null only for
//      lockstep schedules). If neutral: R9 is the declared plateau.
//
// NUMERICS CONTRACT (harness-validated R1-R10, absmax 9.77e-4 exactly):
//  - conv = sequential fma over the 7x7 window, (ky,kx) row-major, one
//    accumulator per direction (bit-exact im path vs the fp32 ref replay).
//  - L/R, NW/NE, SW/SE packed as v_pk_fma lanes; each lane's tap sequence
//    identical to the scalar chain. U/D scalar chains, same tap order.
//  - pi[s][d] = {row[tx+d], row[tx+d+3]}: exactly the operand pair of
//    every packed chain -> zero packing movs.
//  - PERT: quadrant decomposition, trees unchanged since prior-session R5.
//  - setprio is schedule-only: zero effect on values.
template <int NR, int LDW, class F>
__device__ __forceinline__ void ring_pass(
    const float* __restrict__ SI, const float* __restrict__ SP,
    int r0, int tx, F emit)
{
    const float w28 = 1.0f / 28.0f;   // fp32-rounded, as in the ref kernels
    const float w16 = 0.0625f;        // exact
    const v2 w28v = {w28, w28};
    const v2 w16v = {w16, w16};

    v2    pi[7][4];   // pi[slot][d] = {row[tx+d], row[tx+d+3]}
    v2    hlr[7];     // pert row partials {hl, hr}
    float cc[7];      // pert center column

    auto rowload = [&](int slot, int m) {
        const float* rI = SI + m * LDW + tx;
        float w0 = rI[0], w1 = rI[1], w2 = rI[2], w3 = rI[3],
              w4 = rI[4], w5 = rI[5], w6 = rI[6];
        pi[slot][0] = (v2){w0, w3};
        pi[slot][1] = (v2){w1, w4};
        pi[slot][2] = (v2){w2, w5};
        pi[slot][3] = (v2){w3, w6};
        const float* rP = SP + m * LDW + tx;
        float b0 = rP[0], b1 = rP[1], b2 = rP[2], b3 = rP[3],
              b4 = rP[4], b5 = rP[5], b6 = rP[6];
        hlr[slot] = (v2){(b0 + b1) + (b2 + b3), (b3 + b4) + (b5 + b6)};
        cc[slot] = b3;
    };

    #pragma unroll
    for (int m = 0; m < 7; ++m)
        rowload(m, r0 + m);

    #pragma unroll
    for (int jj = 0; jj < NR; ++jj) {
        // ---- im: packed L/R, NW/NE, SW/SE + scalar U, D ----
        v2 aLR = {0.f, 0.f}, aQN = {0.f, 0.f}, aQS = {0.f, 0.f};
        #pragma unroll
        for (int dy = 0; dy < 7; ++dy) {
            const int s = (jj + dy) % 7;
            #pragma unroll
            for (int dx = 0; dx < 4; ++dx)   // L: cols 0..3 | R: cols 3..6
                aLR = __builtin_elementwise_fma(pi[s][dx], w28v, aLR);
        }
        float U = 0.f, Dd = 0.f;
        #pragma unroll
        for (int dy = 0; dy < 4; ++dy) {     // U rows 0..3 | D rows 3..6
            const int su = (jj + dy) % 7;
            const int sd = (jj + dy + 3) % 7;
            // cols 0..6 = pi[0].x pi[1].x pi[2].x pi[3].x pi[1].y pi[2].y pi[3].y
            U = fmaf(pi[su][0].x, w28, U);  U = fmaf(pi[su][1].x, w28, U);
            U = fmaf(pi[su][2].x, w28, U);  U = fmaf(pi[su][3].x, w28, U);
            U = fmaf(pi[su][1].y, w28, U);  U = fmaf(pi[su][2].y, w28, U);
            U = fmaf(pi[su][3].y, w28, U);
            Dd = fmaf(pi[sd][0].x, w28, Dd); Dd = fmaf(pi[sd][1].x, w28, Dd);
            Dd = fmaf(pi[sd][2].x, w28, Dd); Dd = fmaf(pi[sd][3].x, w28, Dd);
            Dd = fmaf(pi[sd][1].y, w28, Dd); Dd = fmaf(pi[sd][2].y, w28, Dd);
            Dd = fmaf(pi[sd][3].y, w28, Dd);
            #pragma unroll
            for (int dx = 0; dx < 4; ++dx) { // NW/NE top rows, SW/SE bottom
                aQN = __builtin_elementwise_fma(pi[su][dx], w16v, aQN);
                aQS = __builtin_elementwise_fma(pi[sd][dx], w16v, aQS);
            }
        }

        const float cI = pi[(jj + 3) % 7][3].x;   // center col 3
        const v2 cI2 = {cI, cI};
        const v2 d01 = aLR - cI2;
        const float d2 = U - cI, d3 = Dd - cI;
        const v2 d45 = aQN - cI2;
        const v2 d67 = aQS - cI2;
        float d[8] = {d01.x, d01.y, d2, d3, d45.x, d45.y, d67.x, d67.y};

        // ---- pert: packed quadrant decomposition (values identical R5) ----
        float e[8];
        const int p0 = (jj + 0) % 7, p1 = (jj + 1) % 7, p2 = (jj + 2) % 7,
                  p3 = (jj + 3) % 7, p4 = (jj + 4) % 7, p5 = (jj + 5) % 7,
                  p6 = (jj + 6) % 7;
        const float cP = cc[p3];
        {
            v2 qN = ((hlr[p0] + hlr[p1]) + (hlr[p2] + hlr[p3])); // (qnw,qne)
            v2 qS = ((hlr[p3] + hlr[p4]) + (hlr[p5] + hlr[p6])); // (qsw,qse)
            float cu = ((cc[p0] + cc[p1]) + (cc[p2] + cc[p3]));
            float cd = ((cc[p3] + cc[p4]) + (cc[p5] + cc[p6]));
            const v2 cP2 = {cP, cP};
            v2 eLR = (qN + qS - hlr[p3]) * w28v - cP2;   // (L, R)
            v2 eQN = qN * w16v - cP2;                    // (NW, NE)
            v2 eQS = qS * w16v - cP2;                    // (SW, SE)
            e[0] = eLR.x;  e[1] = eLR.y;
            e[2] = (qN.x + qN.y - cu) * w28 - cP;        // U
            e[3] = (qS.x + qS.y - cd) * w28 - cP;        // D
            e[4] = eQN.x;  e[5] = eQN.y;
            e[6] = eQS.x;  e[7] = eQS.y;
        }

        // first-index-wins argmin over |d| (jnp.argmin tie-break)
        float bestAbs = fabsf(d[0]);
        float bd = d[0];
        float be = e[0];
        #pragma unroll
        for (int j = 1; j < 8; ++j) {
            float a = fabsf(d[j]);
            bool take = a < bestAbs;
            bestAbs = take ? a : bestAbs;
            bd = take ? d[j] : bd;
            be = take ? e[j] : be;
        }

        emit(jj, cI + bd, cP + be);

        if (jj < NR - 1)
            rowload(jj % 7, r0 + jj + 7);
    }
}

__global__ __launch_bounds__(256) void swf_step(
    const float* __restrict__ im_in, const float* __restrict__ pe_in,
    float* __restrict__ im_out, float* __restrict__ pe_out, int storeIm)
{
    __shared__ float sI[LH * LW];
    __shared__ float sP[LH * LW];

    const int tid = threadIdx.x;
    const int tx = tid & 63;
    const int wv = tid >> 6;          // wave id 0..3
    const int x0 = blockIdx.x * TW;
    const int y0 = blockIdx.y * TH;
    const size_t base = (size_t)blockIdx.z * (size_t)(HH * WW);
    const float* imb = im_in + base;
    const float* peb = pe_in + base;

    // Interior tiles: full halo'd footprint [y0-3,y0+35)x[x0-3,x0+67)
    // in-bounds -> stage rows direct global->LDS (per-lane global src,
    // wave-uniform LDS base + lane*4). Edge tiles: proven masked path.
    const bool interior = (blockIdx.x >= 1) && (blockIdx.x <= 6) &&
                          (blockIdx.y >= 1) && (blockIdx.y <= (HH/TH - 2));
    if (interior) {
        #pragma unroll 1
        for (int r = wv; r < LH; r += 4) {
            const float* gI = imb + (size_t)(y0 - RAD + r) * WW + (x0 - RAD);
            const float* gP = peb + (size_t)(y0 - RAD + r) * WW + (x0 - RAD);
            __builtin_amdgcn_global_load_lds((GPTR)(gI + tx),
                                             (LPTR)(&sI[r * LW]), 4, 0, 0);
            __builtin_amdgcn_global_load_lds((GPTR)(gP + tx),
                                             (LPTR)(&sP[r * LW]), 4, 0, 0);
            if (tx < 6) {
                __builtin_amdgcn_global_load_lds((GPTR)(gI + 64 + tx),
                                                 (LPTR)(&sI[r * LW + 64]), 4, 0, 0);
                __builtin_amdgcn_global_load_lds((GPTR)(gP + 64 + tx),
                                                 (LPTR)(&sP[r * LW + 64]), 4, 0, 0);
            }
        }
    } else {
        for (int i = tid; i < LH * LW; i += 256) {
            int r = i / LW;
            int c = i - r * LW;
            int gy = y0 - RAD + r;
            int gx = x0 - RAD + c;
            bool ok = ((unsigned)gy < (unsigned)HH) && ((unsigned)gx < (unsigned)WW);
            int gi = gy * WW + gx;
            sI[i] = ok ? imb[gi] : 0.0f;
            sP[i] = ok ? peb[gi] : 0.0f;
        }
    }
    __syncthreads();   // compiler emits vmcnt(0)+lgkmcnt(0) drain here

    // Compute phase: raise wave priority so co-resident blocks still in
    // their staging phase yield VALU-issue arbitration to us.
    __builtin_amdgcn_s_setprio(1);

    const int r0 = wv * RPW;          // wave's slab: rows r0 .. r0+RPW+5
    ring_pass<RPW, LW>(&sI[0], &sP[0], r0, tx,
        [&](int jj, float vI, float vP) {
            const size_t gi = base + (size_t)(y0 + r0 + jj) * WW + (x0 + tx);
            if (storeIm) im_out[gi] = vI;
            pe_out[gi] = vP;
        });

    __builtin_amdgcn_s_setprio(0);
}

extern "C" void kernel_launch(void* const* d_in, const int* in_sizes, int n_in,
                              void* d_out, int out_size, void* d_ws, size_t ws_size,
                              hipStream_t stream) {
    const float* im0 = (const float*)d_in[0];
    const float* pe0 = (const float*)d_in[1];
    float* out = (float*)d_out;

    const size_t npix = (size_t)NIMG * HH * WW;   // 3,145,728
    float* imA = (float*)d_ws;                    // 12.6 MB
    float* imB = imA + npix;                      // 12.6 MB
    float* peA = imB + npix;                      // 12.6 MB (ws total 37.7 MB)
    float* peB = out;  // d_out doubles as the second pert buffer; parity
                       // lands the final (iter-5) pert write in d_out.

    dim3 grid(WW / TW, HH / TH, NIMG);            // 8 x 16 x 12 = 1536 blocks
    dim3 block(256);

    swf_step<<<grid, block, 0, stream>>>(im0, pe0, imA, peA, 1);  // iter 0
    swf_step<<<grid, block, 0, stream>>>(imA, peA, imB, peB, 1);  // iter 1
    swf_step<<<grid, block, 0, stream>>>(imB, peB, imA, peA, 1);  // iter 2
    swf_step<<<grid, block, 0, stream>>>(imA, peA, imB, peB, 1);  // iter 3
    swf_step<<<grid, block, 0, stream>>>(imB, peB, imA, peA, 1);  // iter 4
    // iter 5: im store is dead (result = filtered pert only) -> skip
    swf_step<<<grid, block, 0, stream>>>(imA, peA, imB, out, 0);  // iter 5
}